// Round 15
// baseline (37.481 us; speedup 1.0000x reference)
//
#include <hip/hip_runtime.h>
#include <math.h>
#include <float.h>
#include <limits.h>

#define CS    64              // points per chunk (selection granularity)
#define CTP   64              // chunks per pass (== lanes per wave)
#define PASS_PTS (CTP * CS)   // 4096 points staged per pass
#define CSP   65              // chunk stride in float4 (pair-interleaved)
#define QPB   64              // queries per block
#define QT    8               // queries per wave (8 waves x 8 = 64)
#define NPASS 2
#define CMSTRIDE 132          // cminL row stride in floats (16B-aligned rows)
#define MARGIN 0.05f
typedef unsigned long long ull;
typedef float v2f __attribute__((ext_vector_type(2)));
#define KMAX 0xFFFFFFFFFFFFFFFFull

// monotone float -> ordered u32 (handles negatives)
__device__ __forceinline__ unsigned int ford(float f) {
    unsigned int b = __float_as_uint(f);
    return b ^ (((unsigned int)((int)b >> 31)) | 0x80000000u);
}
__device__ __forceinline__ float funord(unsigned int u) {
    unsigned int m = ((u >> 31) - 1u) | 0x80000000u;
    return __uint_as_float(u ^ m);
}

__device__ __forceinline__ ull umin64(ull a, ull b) { return a < b ? a : b; }
__device__ __forceinline__ ull umax64(ull a, ull b) { return a > b ? a : b; }

// branchless sorted-3 insert on u64 keys (k0<=k1<=k2), lex (d,idx) tie-break
__device__ __forceinline__ void ins3k(ull k, ull& k0, ull& k1, ull& k2) {
    ull n2 = umax64(k1, umin64(k2, k));
    ull n1 = umax64(k0, umin64(k1, k));
    k0 = umin64(k0, k);
    k1 = n1;
    k2 = n2;
}

// branchless sorted-3 insert, f32 values only
__device__ __forceinline__ void sins(float d, float& a0, float& a1, float& a2)
{
    float n1 = __builtin_amdgcn_fmed3f(a0, a1, d);
    float n2 = __builtin_amdgcn_fmed3f(a1, a2, d);
    a0 = fminf(a0, d);
    a1 = n1;
    a2 = n2;
}

// pose_0to1 = inv(pose1) @ pose0 (SE3 analytic)
__device__ __forceinline__ void pose_rel(const float* __restrict__ P0,
                                         const float* __restrict__ P1,
                                         float R[3][3], float tv[3])
{
    float dt0 = P0[3]  - P1[3];
    float dt1 = P0[7]  - P1[7];
    float dt2 = P0[11] - P1[11];
    #pragma unroll
    for (int i = 0; i < 3; ++i) {
        float a0 = P1[i], a1 = P1[4 + i], a2 = P1[8 + i];   // col i of R1
        #pragma unroll
        for (int j = 0; j < 3; ++j)
            R[i][j] = fmaf(a2, P0[8 + j], fmaf(a1, P0[4 + j], a0 * P0[j]));
        tv[i] = fmaf(a2, dt2, fmaf(a1, dt1, a0 * dt0));
    }
}

// ---------------- fused single kernel: 2-pass LDS scan + in-block select ----
__launch_bounds__(512, 2)
__global__ void knn_fused(const float* __restrict__ pc0,
                          const float* __restrict__ pc1,
                          const float* __restrict__ flow1,
                          const float* __restrict__ pose0,
                          const float* __restrict__ pose1,
                          float* __restrict__ out,
                          int B, int N, int M)
{
    __shared__ float4 tile[CTP * CSP];   // 66.6 KB; reused as cminL after scan
    __shared__ float4 qd[QPB];           // (qx,qy,qz,q2)

    const int tid = threadIdx.x;
    const int b   = blockIdx.y;
    const int qb  = blockIdx.x * QPB;

    // ---- setup: 64 transformed queries + pose_flow output ----
    if (tid < QPB) {
        float R[3][3], tv[3];
        pose_rel(pose0 + b * 16, pose1 + b * 16, R, tv);
        int qg0 = qb + tid;
        bool valid = qg0 < N;
        int qg = valid ? qg0 : (N - 1);
        const float px = pc0[(size_t)(b * N + qg) * 3 + 0];
        const float py = pc0[(size_t)(b * N + qg) * 3 + 1];
        const float pz = pc0[(size_t)(b * N + qg) * 3 + 2];
        float qx = fmaf(R[0][2], pz, fmaf(R[0][1], py, R[0][0] * px)) + tv[0];
        float qy = fmaf(R[1][2], pz, fmaf(R[1][1], py, R[1][0] * px)) + tv[1];
        float qz = fmaf(R[2][2], pz, fmaf(R[2][1], py, R[2][0] * px)) + tv[2];
        qd[tid] = make_float4(qx, qy, qz, (qx * qx + qy * qy) + qz * qz);
        if (valid) {
            size_t pf = (size_t)B * N * 3 + (size_t)(b * N + qg) * 3;
            out[pf + 0] = qx - px;
            out[pf + 1] = qy - py;
            out[pf + 2] = qz - pz;
        }
    }
    __syncthreads();                      // qd ready

    const int w    = tid >> 6;            // wave 0..7
    const int lane = tid & 63;            // lane == chunk within pass

    // query splats for this wave's 8 queries
    v2f qx2[QT], qy2[QT], qz2[QT];
    #pragma unroll
    for (int t = 0; t < QT; ++t) {
        float4 qq = qd[w * QT + t];
        qx2[t] = (v2f)(qq.x);
        qy2[t] = (v2f)(qq.y);
        qz2[t] = (v2f)(qq.z);
    }

    float mm[NPASS][QT];
    #pragma unroll
    for (int pp = 0; pp < NPASS; ++pp)
        #pragma unroll
        for (int t = 0; t < QT; ++t) mm[pp][t] = FLT_MAX;

    for (int pass = 0; pass < NPASS; ++pass) {
        if (pass) __syncthreads();        // previous pass's scan reads done

        // ---- stage PASS_PTS points, pair-interleaved (-2x,-2y,-2z,r2) ----
        #pragma unroll
        for (int k = 0; k < PASS_PTS / (512 * 4); ++k) {   // 2 rounds
            const int pl = (tid + k * 512) * 4;            // local pt, %4==0
            const int p  = pass * PASS_PTS + pl;           // pt in batch
            const int c  = pl >> 6;
            const int off = pl & (CS - 1);
            float4* dst = &tile[c * CSP + off];
            float x0,y0,z0, x1,y1,z1, x2,y2,z2, x3,y3,z3;
            if (p + 3 < M) {
                const float4* pf = (const float4*)(pc1 + (size_t)(b * M + p) * 3);
                float4 A = pf[0], Bv = pf[1], C = pf[2];
                x0 = A.x;  y0 = A.y;  z0 = A.z;
                x1 = A.w;  y1 = Bv.x; z1 = Bv.y;
                x2 = Bv.z; y2 = Bv.w; z2 = C.x;
                x3 = C.y;  y3 = C.z;  z3 = C.w;
            } else {
                float tx[4], ty[4], tz[4];
                #pragma unroll
                for (int u = 0; u < 4; ++u) {
                    int pp2 = p + u;
                    if (pp2 < M) {
                        const float* s = pc1 + (size_t)(b * M + pp2) * 3;
                        tx[u] = s[0]; ty[u] = s[1]; tz[u] = s[2];
                    } else {
                        tx[u] = 0.f; ty[u] = 0.f; tz[u] = 0.f;
                    }
                }
                x0 = tx[0]; y0 = ty[0]; z0 = tz[0];
                x1 = tx[1]; y1 = ty[1]; z1 = tz[1];
                x2 = tx[2]; y2 = ty[2]; z2 = tz[2];
                x3 = tx[3]; y3 = ty[3]; z3 = tz[3];
            }
            float r0 = (p + 0 < M) ? (x0 * x0 + y0 * y0) + z0 * z0 : FLT_MAX;
            float r1 = (p + 1 < M) ? (x1 * x1 + y1 * y1) + z1 * z1 : FLT_MAX;
            float r2 = (p + 2 < M) ? (x2 * x2 + y2 * y2) + z2 * z2 : FLT_MAX;
            float r3 = (p + 3 < M) ? (x3 * x3 + y3 * y3) + z3 * z3 : FLT_MAX;
            dst[0] = make_float4(-2.f * x0, -2.f * x1, -2.f * y0, -2.f * y1);
            dst[1] = make_float4(-2.f * z0, -2.f * z1, r0, r1);
            dst[2] = make_float4(-2.f * x2, -2.f * x3, -2.f * y2, -2.f * y3);
            dst[3] = make_float4(-2.f * z2, -2.f * z3, r2, r3);
        }
        __syncthreads();

        // ---- scan: lane owns chunk `lane`; 32 pairs; pk-fma (bit == scalar) --
        const float4* tp = &tile[lane * CSP];
        #pragma unroll 4
        for (int i = 0; i < 32; ++i) {
            const float4 xy = tp[2 * i];
            const float4 zw = tp[2 * i + 1];
            v2f X = {xy.x, xy.y};
            v2f Y = {xy.z, xy.w};
            v2f Z = {zw.x, zw.y};
            v2f W = {zw.z, zw.w};
            #pragma unroll
            for (int t = 0; t < QT; ++t) {
                v2f kk;
                asm("v_pk_fma_f32 %0, %1, %2, %3"
                    : "=v"(kk) : "v"(Z), "v"(qz2[t]), "v"(W));
                asm("v_pk_fma_f32 %0, %1, %2, %0"
                    : "+v"(kk) : "v"(Y), "v"(qy2[t]));
                asm("v_pk_fma_f32 %0, %1, %2, %0"
                    : "+v"(kk) : "v"(X), "v"(qx2[t]));
                mm[pass][t] = fminf(mm[pass][t], fminf(kk.x, kk.y));
            }
        }
    }

    __syncthreads();                       // all scan reads of tile complete

    // ---- write per-query chunk-min rows into re-used tile LDS ----
    float* cminL = (float*)tile;           // 64 rows x CMSTRIDE floats (33.8KB)
    #pragma unroll
    for (int t = 0; t < QT; ++t) {
        const int ql = w * QT + t;
        cminL[ql * CMSTRIDE + lane]       = mm[0][t];
        cminL[ql * CMSTRIDE + CTP + lane] = mm[1][t];
    }
    __syncthreads();

    // ================== phase B: 32 groups x 16 lanes, 2 rounds ==============
    const int g = tid >> 4;        // group 0..31
    const int l = tid & 15;        // lane within group

    for (int round = 0; round < QPB / 32; ++round) {
        const int ql = round * 32 + g;
        const int q0 = qb + ql;
        const bool qvalid = (q0 < N);
        const int q = qvalid ? q0 : (N - 1);

        const float4 sA = *(const float4*)&cminL[ql * CMSTRIDE + l * 8];
        const float4 sB = *(const float4*)&cminL[ql * CMSTRIDE + l * 8 + 4];
        const float4 qq = qd[ql];
        const float qx = qq.x, qy = qq.y, qz = qq.z, q2 = qq.w;

        // threshold: 3rd-smallest of 128 chunk-mins (8/lane + 4-level bfly)
        float a0 = FLT_MAX, a1 = FLT_MAX, a2 = FLT_MAX;
        sins(sA.x, a0, a1, a2); sins(sA.y, a0, a1, a2);
        sins(sA.z, a0, a1, a2); sins(sA.w, a0, a1, a2);
        sins(sB.x, a0, a1, a2); sins(sB.y, a0, a1, a2);
        sins(sB.z, a0, a1, a2); sins(sB.w, a0, a1, a2);
        #pragma unroll
        for (int msk = 1; msk <= 8; msk <<= 1) {
            float o0 = __shfl_xor(a0, msk);
            float o1 = __shfl_xor(a1, msk);
            float o2 = __shfl_xor(a2, msk);
            sins(o0, a0, a1, a2);
            sins(o1, a0, a1, a2);
            sins(o2, a0, a1, a2);
        }
        const float thr = a2 + MARGIN;

        // two 64-bit chunk masks (chunks 0..63, 64..127), OR-butterfly
        unsigned int mbits =
              ((unsigned int)(sA.x <= thr) << 0) | ((unsigned int)(sA.y <= thr) << 1)
            | ((unsigned int)(sA.z <= thr) << 2) | ((unsigned int)(sA.w <= thr) << 3)
            | ((unsigned int)(sB.x <= thr) << 4) | ((unsigned int)(sB.y <= thr) << 5)
            | ((unsigned int)(sB.z <= thr) << 6) | ((unsigned int)(sB.w <= thr) << 7);
        ull m0 = (l < 8) ? ((ull)mbits << (8 * l)) : 0ull;
        ull m1 = (l >= 8) ? ((ull)mbits << (8 * (l - 8))) : 0ull;
        #pragma unroll
        for (int msk = 1; msk <= 8; msk <<= 1) {
            m0 |= __shfl_xor(m0, msk);
            m1 |= __shfl_xor(m1, msk);
        }

        // dense rescan of selected 64-pt chunks from RAW pc1 (exact ref path)
        ull kA0 = KMAX, kA1 = KMAX, kA2 = KMAX;
        ull kB0 = KMAX, kB1 = KMAX, kB2 = KMAX;
        #pragma unroll
        for (int half = 0; half < 2; ++half) {
            ull mask = half ? m1 : m0;
            const int cbase = half * 64;
            while (mask) {
                const int ck = (int)__builtin_ctzll(mask);
                mask &= mask - 1;
                const int mb = (cbase + ck) * CS;
                #pragma unroll
                for (int r = 0; r < CS / 16; ++r) {
                    const int m = mb + r * 16 + l;
                    if (m < M) {
                        const float* pp = pc1 + (size_t)(b * M + m) * 3;
                        float x = pp[0], y = pp[1], z = pp[2];
                        float r2 = (x * x + y * y) + z * z;
                        float cr = fmaf(qz, z, fmaf(qy, y, qx * x));
                        float dd = fmaf(-2.0f, cr, q2 + r2);   // exact ref rounding
                        ull kk = ((ull)ford(dd) << 32) | (unsigned int)m;
                        if (r & 1) ins3k(kk, kB0, kB1, kB2);
                        else       ins3k(kk, kA0, kA1, kA2);
                    }
                }
            }
        }
        ins3k(kB0, kA0, kA1, kA2);
        ins3k(kB1, kA0, kA1, kA2);
        ins3k(kB2, kA0, kA1, kA2);

        // merge 16 lanes: 4-level butterfly of sorted triples
        #pragma unroll
        for (int msk = 1; msk <= 8; msk <<= 1) {
            ull o0 = __shfl_xor(kA0, msk);
            ull o1 = __shfl_xor(kA1, msk);
            ull o2 = __shfl_xor(kA2, msk);
            ins3k(o0, kA0, kA1, kA2);
            ins3k(o1, kA0, kA1, kA2);
            ins3k(o2, kA0, kA1, kA2);
        }

        if (l == 0 && qvalid) {
            float D0 = funord((unsigned int)(kA0 >> 32));
            float D1 = funord((unsigned int)(kA1 >> 32));
            float D2 = funord((unsigned int)(kA2 >> 32));
            int   i0 = (int)(unsigned int)kA0;
            int   i1 = (int)(unsigned int)kA1;
            int   i2 = (int)(unsigned int)kA2;

            float dd0 = sqrtf(fmaxf(D0, 0.f));
            float dd1 = sqrtf(fmaxf(D1, 0.f));
            float dd2 = sqrtf(fmaxf(D2, 0.f));
            float w0 = 1.0f / (dd0 + 1e-8f);
            float w1 = 1.0f / (dd1 + 1e-8f);
            float w2 = 1.0f / (dd2 + 1e-8f);
            float wsum = (w0 + w1) + w2;
            w0 /= wsum; w1 /= wsum; w2 /= wsum;

            const float* f0 = flow1 + (size_t)(b * M + i0) * 3;
            const float* f1 = flow1 + (size_t)(b * M + i1) * 3;
            const float* f2 = flow1 + (size_t)(b * M + i2) * 3;

            const size_t ob = (size_t)(b * N + q) * 3;
            #pragma unroll
            for (int c = 0; c < 3; ++c) {
                float p0 = w0 * f0[c];
                float p1 = w1 * f1[c];
                float p2 = w2 * f2[c];
                out[ob + c] = (p0 + p1) + p2;
            }
        }
    }
}

extern "C" void kernel_launch(void* const* d_in, const int* in_sizes, int n_in,
                              void* d_out, int out_size, void* d_ws, size_t ws_size,
                              hipStream_t stream) {
    const float* pc0   = (const float*)d_in[0];
    const float* pc1   = (const float*)d_in[1];
    const float* flow1 = (const float*)d_in[2];
    const float* pose0 = (const float*)d_in[3];
    const float* pose1 = (const float*)d_in[4];
    float* out = (float*)d_out;

    const int B = in_sizes[3] / 16;
    const int N = in_sizes[0] / (3 * B);
    const int M = in_sizes[1] / (3 * B);

    dim3 grid((N + QPB - 1) / QPB, B);
    knn_fused<<<grid, dim3(512), 0, stream>>>(pc0, pc1, flow1, pose0, pose1,
                                              out, B, N, M);
}

// Round 16
// 34.361 us; speedup vs baseline: 1.0908x; 1.0908x over previous
//
#include <hip/hip_runtime.h>
#include <math.h>
#include <float.h>
#include <limits.h>

#define CS    64              // points per chunk (selection granularity)
#define CTP   64              // chunks per pass (== lanes per wave)
#define PASS_PTS (CTP * CS)   // 4096 points staged per pass
#define QPB   64              // queries per block
#define QT    8               // queries per wave (8 waves x 8 = 64)
#define NPASS 2
#define CMSTRIDE 132          // cminL row stride in floats (16B-aligned rows)
#define MARGIN 0.05f
typedef unsigned long long ull;
#define KMAX 0xFFFFFFFFFFFFFFFFull

// monotone float -> ordered u32 (handles negatives)
__device__ __forceinline__ unsigned int ford(float f) {
    unsigned int b = __float_as_uint(f);
    return b ^ (((unsigned int)((int)b >> 31)) | 0x80000000u);
}
__device__ __forceinline__ float funord(unsigned int u) {
    unsigned int m = ((u >> 31) - 1u) | 0x80000000u;
    return __uint_as_float(u ^ m);
}

__device__ __forceinline__ ull umin64(ull a, ull b) { return a < b ? a : b; }
__device__ __forceinline__ ull umax64(ull a, ull b) { return a > b ? a : b; }

// branchless sorted-3 insert on u64 keys (k0<=k1<=k2), lex (d,idx) tie-break
__device__ __forceinline__ void ins3k(ull k, ull& k0, ull& k1, ull& k2) {
    ull n2 = umax64(k1, umin64(k2, k));
    ull n1 = umax64(k0, umin64(k1, k));
    k0 = umin64(k0, k);
    k1 = n1;
    k2 = n2;
}

// branchless sorted-3 insert, f32 values only
__device__ __forceinline__ void sins(float d, float& a0, float& a1, float& a2)
{
    float n1 = __builtin_amdgcn_fmed3f(a0, a1, d);
    float n2 = __builtin_amdgcn_fmed3f(a1, a2, d);
    a0 = fminf(a0, d);
    a1 = n1;
    a2 = n2;
}

// pose_0to1 = inv(pose1) @ pose0 (SE3 analytic)
__device__ __forceinline__ void pose_rel(const float* __restrict__ P0,
                                         const float* __restrict__ P1,
                                         float R[3][3], float tv[3])
{
    float dt0 = P0[3]  - P1[3];
    float dt1 = P0[7]  - P1[7];
    float dt2 = P0[11] - P1[11];
    #pragma unroll
    for (int i = 0; i < 3; ++i) {
        float a0 = P1[i], a1 = P1[4 + i], a2 = P1[8 + i];   // col i of R1
        #pragma unroll
        for (int j = 0; j < 3; ++j)
            R[i][j] = fmaf(a2, P0[8 + j], fmaf(a1, P0[4 + j], a0 * P0[j]));
        tv[i] = fmaf(a2, dt2, fmaf(a1, dt1, a0 * dt0));
    }
}

// ---------------- fused single kernel: 2-pass LDS scan + in-block select ----
__launch_bounds__(512, 2)
__global__ void knn_fused(const float* __restrict__ pc0,
                          const float* __restrict__ pc1,
                          const float* __restrict__ flow1,
                          const float* __restrict__ pose0,
                          const float* __restrict__ pose1,
                          float* __restrict__ out,
                          int B, int N, int M)
{
    __shared__ float4 tile[PASS_PTS];    // 64 KB, LINEAR; reused as cminL
    __shared__ float4 qd[QPB];           // (qx,qy,qz,q2)

    const int tid = threadIdx.x;
    const int b   = blockIdx.y;
    const int qb  = blockIdx.x * QPB;

    // ---- setup: 64 transformed queries + pose_flow output ----
    if (tid < QPB) {
        float R[3][3], tv[3];
        pose_rel(pose0 + b * 16, pose1 + b * 16, R, tv);
        int qg0 = qb + tid;
        bool valid = qg0 < N;
        int qg = valid ? qg0 : (N - 1);
        const float px = pc0[(size_t)(b * N + qg) * 3 + 0];
        const float py = pc0[(size_t)(b * N + qg) * 3 + 1];
        const float pz = pc0[(size_t)(b * N + qg) * 3 + 2];
        float qx = fmaf(R[0][2], pz, fmaf(R[0][1], py, R[0][0] * px)) + tv[0];
        float qy = fmaf(R[1][2], pz, fmaf(R[1][1], py, R[1][0] * px)) + tv[1];
        float qz = fmaf(R[2][2], pz, fmaf(R[2][1], py, R[2][0] * px)) + tv[2];
        qd[tid] = make_float4(qx, qy, qz, (qx * qx + qy * qy) + qz * qz);
        if (valid) {
            size_t pf = (size_t)B * N * 3 + (size_t)(b * N + qg) * 3;
            out[pf + 0] = qx - px;
            out[pf + 1] = qy - py;
            out[pf + 2] = qz - pz;
        }
    }
    __syncthreads();                      // qd ready

    const int w    = tid >> 6;            // wave 0..7
    const int lane = tid & 63;            // lane == chunk within pass

    float4 qv[QT];
    #pragma unroll
    for (int t = 0; t < QT; ++t) qv[t] = qd[w * QT + t];

    float mm[NPASS][QT];
    #pragma unroll
    for (int pp = 0; pp < NPASS; ++pp)
        #pragma unroll
        for (int t = 0; t < QT; ++t) mm[pp][t] = FLT_MAX;

    for (int pass = 0; pass < NPASS; ++pass) {
        if (pass) __syncthreads();        // previous pass's scan reads done

        // ---- stage PASS_PTS points LINEAR: tile[pl] = (-2x,-2y,-2z,r2) ----
        #pragma unroll
        for (int k = 0; k < PASS_PTS / (512 * 4); ++k) {   // 2 rounds
            const int pl = (tid + k * 512) * 4;            // local pt, %4==0
            const int p  = pass * PASS_PTS + pl;           // pt in batch
            float4* dst = &tile[pl];
            if (p + 3 < M) {
                const float4* pf = (const float4*)(pc1 + (size_t)(b * M + p) * 3);
                float4 A = pf[0], Bv = pf[1], C = pf[2];
                dst[0] = make_float4(-2.f * A.x, -2.f * A.y, -2.f * A.z,
                                     (A.x * A.x + A.y * A.y) + A.z * A.z);
                dst[1] = make_float4(-2.f * A.w, -2.f * Bv.x, -2.f * Bv.y,
                                     (A.w * A.w + Bv.x * Bv.x) + Bv.y * Bv.y);
                dst[2] = make_float4(-2.f * Bv.z, -2.f * Bv.w, -2.f * C.x,
                                     (Bv.z * Bv.z + Bv.w * Bv.w) + C.x * C.x);
                dst[3] = make_float4(-2.f * C.y, -2.f * C.z, -2.f * C.w,
                                     (C.y * C.y + C.z * C.z) + C.w * C.w);
            } else {
                #pragma unroll
                for (int u = 0; u < 4; ++u) {
                    int pp2 = p + u;
                    float4 v;
                    if (pp2 < M) {
                        const float* s = pc1 + (size_t)(b * M + pp2) * 3;
                        float x = s[0], y = s[1], z = s[2];
                        v = make_float4(-2.f * x, -2.f * y, -2.f * z,
                                        (x * x + y * y) + z * z);
                    } else {
                        v = make_float4(0.f, 0.f, 0.f, FLT_MAX);
                    }
                    dst[u] = v;
                }
            }
        }
        __syncthreads();

        // ---- scan: lane owns chunk `lane`; ROTATED slot order (i+lane)&63 --
        // At step i, lane L's b128 sits at bank-quad (i+L)&7 -> 8 lanes/quad
        // = uniform minimum-phase access: conflict-free. Min is order-
        // independent -> chunk-min bit-identical to sequential order.
        const float4* cb = &tile[lane << 6];
        #pragma unroll 4
        for (int i = 0; i < CS; ++i) {
            const float4 v = cb[(i + lane) & (CS - 1)];
            #pragma unroll
            for (int t = 0; t < QT; ++t)
                mm[pass][t] = fminf(mm[pass][t],
                    fmaf(qv[t].x, v.x, fmaf(qv[t].y, v.y, fmaf(qv[t].z, v.z, v.w))));
        }
    }

    __syncthreads();                       // all scan reads of tile complete

    // ---- write per-query chunk-min rows into re-used tile LDS ----
    float* cminL = (float*)tile;           // 64 rows x CMSTRIDE floats (33.8KB)
    #pragma unroll
    for (int t = 0; t < QT; ++t) {
        const int ql = w * QT + t;
        cminL[ql * CMSTRIDE + lane]       = mm[0][t];
        cminL[ql * CMSTRIDE + CTP + lane] = mm[1][t];
    }
    __syncthreads();

    // ================== phase B: 32 groups x 16 lanes, 2 rounds ==============
    const int g = tid >> 4;        // group 0..31
    const int l = tid & 15;        // lane within group

    for (int round = 0; round < QPB / 32; ++round) {
        const int ql = round * 32 + g;
        const int q0 = qb + ql;
        const bool qvalid = (q0 < N);
        const int q = qvalid ? q0 : (N - 1);

        const float4 sA = *(const float4*)&cminL[ql * CMSTRIDE + l * 8];
        const float4 sB = *(const float4*)&cminL[ql * CMSTRIDE + l * 8 + 4];
        const float4 qq = qd[ql];
        const float qx = qq.x, qy = qq.y, qz = qq.z, q2 = qq.w;

        // threshold: 3rd-smallest of 128 chunk-mins (8/lane + 4-level bfly)
        float a0 = FLT_MAX, a1 = FLT_MAX, a2 = FLT_MAX;
        sins(sA.x, a0, a1, a2); sins(sA.y, a0, a1, a2);
        sins(sA.z, a0, a1, a2); sins(sA.w, a0, a1, a2);
        sins(sB.x, a0, a1, a2); sins(sB.y, a0, a1, a2);
        sins(sB.z, a0, a1, a2); sins(sB.w, a0, a1, a2);
        #pragma unroll
        for (int msk = 1; msk <= 8; msk <<= 1) {
            float o0 = __shfl_xor(a0, msk);
            float o1 = __shfl_xor(a1, msk);
            float o2 = __shfl_xor(a2, msk);
            sins(o0, a0, a1, a2);
            sins(o1, a0, a1, a2);
            sins(o2, a0, a1, a2);
        }
        const float thr = a2 + MARGIN;

        // two 64-bit chunk masks (chunks 0..63, 64..127), OR-butterfly
        unsigned int mbits =
              ((unsigned int)(sA.x <= thr) << 0) | ((unsigned int)(sA.y <= thr) << 1)
            | ((unsigned int)(sA.z <= thr) << 2) | ((unsigned int)(sA.w <= thr) << 3)
            | ((unsigned int)(sB.x <= thr) << 4) | ((unsigned int)(sB.y <= thr) << 5)
            | ((unsigned int)(sB.z <= thr) << 6) | ((unsigned int)(sB.w <= thr) << 7);
        ull m0 = (l < 8) ? ((ull)mbits << (8 * l)) : 0ull;
        ull m1 = (l >= 8) ? ((ull)mbits << (8 * (l - 8))) : 0ull;
        #pragma unroll
        for (int msk = 1; msk <= 8; msk <<= 1) {
            m0 |= __shfl_xor(m0, msk);
            m1 |= __shfl_xor(m1, msk);
        }

        // dense rescan of selected 64-pt chunks from RAW pc1 (exact ref path)
        ull kA0 = KMAX, kA1 = KMAX, kA2 = KMAX;
        ull kB0 = KMAX, kB1 = KMAX, kB2 = KMAX;
        #pragma unroll
        for (int half = 0; half < 2; ++half) {
            ull mask = half ? m1 : m0;
            const int cbase = half * 64;
            while (mask) {
                const int ck = (int)__builtin_ctzll(mask);
                mask &= mask - 1;
                const int mb = (cbase + ck) * CS;
                #pragma unroll
                for (int r = 0; r < CS / 16; ++r) {
                    const int m = mb + r * 16 + l;
                    if (m < M) {
                        const float* pp = pc1 + (size_t)(b * M + m) * 3;
                        float x = pp[0], y = pp[1], z = pp[2];
                        float r2 = (x * x + y * y) + z * z;
                        float cr = fmaf(qz, z, fmaf(qy, y, qx * x));
                        float dd = fmaf(-2.0f, cr, q2 + r2);   // exact ref rounding
                        ull kk = ((ull)ford(dd) << 32) | (unsigned int)m;
                        if (r & 1) ins3k(kk, kB0, kB1, kB2);
                        else       ins3k(kk, kA0, kA1, kA2);
                    }
                }
            }
        }
        ins3k(kB0, kA0, kA1, kA2);
        ins3k(kB1, kA0, kA1, kA2);
        ins3k(kB2, kA0, kA1, kA2);

        // merge 16 lanes: 4-level butterfly of sorted triples
        #pragma unroll
        for (int msk = 1; msk <= 8; msk <<= 1) {
            ull o0 = __shfl_xor(kA0, msk);
            ull o1 = __shfl_xor(kA1, msk);
            ull o2 = __shfl_xor(kA2, msk);
            ins3k(o0, kA0, kA1, kA2);
            ins3k(o1, kA0, kA1, kA2);
            ins3k(o2, kA0, kA1, kA2);
        }

        if (l == 0 && qvalid) {
            float D0 = funord((unsigned int)(kA0 >> 32));
            float D1 = funord((unsigned int)(kA1 >> 32));
            float D2 = funord((unsigned int)(kA2 >> 32));
            int   i0 = (int)(unsigned int)kA0;
            int   i1 = (int)(unsigned int)kA1;
            int   i2 = (int)(unsigned int)kA2;

            float dd0 = sqrtf(fmaxf(D0, 0.f));
            float dd1 = sqrtf(fmaxf(D1, 0.f));
            float dd2 = sqrtf(fmaxf(D2, 0.f));
            float w0 = 1.0f / (dd0 + 1e-8f);
            float w1 = 1.0f / (dd1 + 1e-8f);
            float w2 = 1.0f / (dd2 + 1e-8f);
            float wsum = (w0 + w1) + w2;
            w0 /= wsum; w1 /= wsum; w2 /= wsum;

            const float* f0 = flow1 + (size_t)(b * M + i0) * 3;
            const float* f1 = flow1 + (size_t)(b * M + i1) * 3;
            const float* f2 = flow1 + (size_t)(b * M + i2) * 3;

            const size_t ob = (size_t)(b * N + q) * 3;
            #pragma unroll
            for (int c = 0; c < 3; ++c) {
                float p0 = w0 * f0[c];
                float p1 = w1 * f1[c];
                float p2 = w2 * f2[c];
                out[ob + c] = (p0 + p1) + p2;
            }
        }
    }
}

extern "C" void kernel_launch(void* const* d_in, const int* in_sizes, int n_in,
                              void* d_out, int out_size, void* d_ws, size_t ws_size,
                              hipStream_t stream) {
    const float* pc0   = (const float*)d_in[0];
    const float* pc1   = (const float*)d_in[1];
    const float* flow1 = (const float*)d_in[2];
    const float* pose0 = (const float*)d_in[3];
    const float* pose1 = (const float*)d_in[4];
    float* out = (float*)d_out;

    const int B = in_sizes[3] / 16;
    const int N = in_sizes[0] / (3 * B);
    const int M = in_sizes[1] / (3 * B);

    dim3 grid((N + QPB - 1) / QPB, B);
    knn_fused<<<grid, dim3(512), 0, stream>>>(pc0, pc1, flow1, pose0, pose1,
                                              out, B, N, M);
}